// Round 9
// baseline (91702.100 us; speedup 1.0000x reference)
//
#include <hip/hip_runtime.h>
#include <hip/hip_bf16.h>

// Problem constants
constexpr int kN = 8192;
constexpr int kF = 256;
constexpr int kH = 512;
constexpr int kL = 512;
constexpr int kE = kN * 4;           // 32768 edges
constexpr int BPD = 16;              // blocks per direction
constexpr int THR = 512;             // threads per block

using ull = unsigned long long;

__device__ __forceinline__ float sigm(float x) { return 1.f / (1.f + __expf(-x)); }

__device__ __forceinline__ float4 ld_bf4(const __hip_bfloat16* p) {
    uint2 u = *(const uint2*)p;
    float4 r;
    r.x = __uint_as_float(u.x << 16);
    r.y = __uint_as_float(u.x & 0xffff0000u);
    r.z = __uint_as_float(u.y << 16);
    r.w = __uint_as_float(u.y & 0xffff0000u);
    return r;
}

// stamped 8-byte pair: low = float bits, high = stamp (publish step + 1)
// relaxed agent-scope atomics: the only encoding that both pipelines and is
// safe (volatile -> serialized vmcnt(0) [r6]; cache-op tricks -> fault [r8]).
__device__ __forceinline__ void st_pair(ull* p, float v, unsigned stamp) {
    ull u = ((ull)stamp << 32) | (ull)__float_as_uint(v);
    __hip_atomic_store(p, u, __ATOMIC_RELAXED, __HIP_MEMORY_SCOPE_AGENT);
}
__device__ __forceinline__ ull ld_pair(const ull* p) {
    return __hip_atomic_load(p, __ATOMIC_RELAXED, __HIP_MEMORY_SCOPE_AGENT);
}

// ---------------------------------------------------------------------------
__global__ void k_init(float* __restrict__ out, const float* __restrict__ bdo,
                       ull* __restrict__ hpay, ull* __restrict__ zpay,
                       int* __restrict__ claims) {
    int idx = blockIdx.x * 256 + threadIdx.x;
    if (idx < kE) out[idx] = bdo[0];
    if (idx < 2 * 2 * 4 * kH) hpay[idx] = 0ull;
    if (idx < 2 * 2 * BPD * 256) zpay[idx] = 0ull;
    if (idx < 2) claims[idx] = 0;
}

__global__ void k_zero(float* __restrict__ out) {
    int idx = blockIdx.x * 256 + threadIdx.x;
    if (idx < kE) out[idx] = 0.f;
}

// ---------------------------------------------------------------------------
// Recurrent kernel: 512 candidate blocks, 512 threads; 16 working blocks per
// direction claimed by XCD (XCD0 fwd, XCD1 bwd, late fallback). Block b owns
// h-dims [b*32, b*32+32) -> 128 gate rows; Whh slice in VGPRs, Wih streamed.
// Per-step order: prefetch -> matvec -> XFIN(next, parity buf) -> cell +
// publish -> resolve (NO barrier between publish and resolve) -> combine.
// Own-block contributions come from LDS/regs, never from MALL.
// ---------------------------------------------------------------------------
__global__ __launch_bounds__(THR, 2) void k_recur(
    const float* __restrict__ edges,
    const float* __restrict__ Wih_f, const float* __restrict__ Whh_f, const float* __restrict__ b_f,
    const float* __restrict__ Wih_b, const float* __restrict__ Whh_b, const float* __restrict__ b_b,
    const float* __restrict__ Wa, const float* __restrict__ ba,
    const float* __restrict__ Wao, const float* __restrict__ bao,
    __hip_bfloat16* __restrict__ arc_f, __hip_bfloat16* __restrict__ arc_b,
    ull* __restrict__ hpay, ull* __restrict__ zpay, int* __restrict__ claims) {

    // ---- XCD-affine slot claim ----
    __shared__ int s_slot;
    if (threadIdx.x == 0) {
        unsigned xcc = (unsigned)__builtin_amdgcn_s_getreg((31 << 11) | (0 << 6) | 20) & 15u;
        int slot = -1;
        if (xcc <= 1) {
            int c = atomicAdd(&claims[xcc], 1);
            if (c < BPD) slot = (int)xcc * BPD + c;
        } else {
            for (int sl = 0; sl < 64; sl++) __builtin_amdgcn_s_sleep(64);
            for (int dd = 0; dd < 2 && slot < 0; dd++) {
                if (__hip_atomic_load(&claims[dd], __ATOMIC_RELAXED,
                                      __HIP_MEMORY_SCOPE_AGENT) < BPD) {
                    int c = atomicAdd(&claims[dd], 1);
                    if (c < BPD) slot = dd * BPD + c;
                }
            }
        }
        s_slot = slot;
    }
    __syncthreads();
    const int slot = s_slot;
    if (slot < 0) return;
    const int dir = slot >> 4;
    const int bl  = slot & 15;

    const float* __restrict__ Whh = dir ? Whh_b : Whh_f;
    const float* __restrict__ Wih = dir ? Wih_b : Wih_f;
    const float* __restrict__ bia = dir ? b_b  : b_f;
    __hip_bfloat16* __restrict__ arc = dir ? arc_b : arc_f;
    const int tid = threadIdx.x;

    // matvec roles: 128 gate rows x 4-way K split
    const int jl = tid >> 2, ks = tid & 3;                 // jl in [0,128)
    const int Jg = (jl >> 5) * kH + bl * 32 + (jl & 31);
    // XFIN / cell / z roles: d-group = tid>>7 (4 groups of 128)
    const int d_gx = tid >> 7, jlx = tid & 127;
    const int Jg2 = (jlx >> 5) * kH + bl * 32 + (jlx & 31);
    const int a_id = jlx & 63;

    float w[128];
    {
        const float* wr = Whh + (size_t)Jg * kH + ks * 128;
        #pragma unroll
        for (int kk = 0; kk < 128; kk++) w[kk] = wr[kk];
    }
    const float* wihr = Wih + (size_t)Jg2 * kF + d_gx * 64;   // streamed per step
    const float biasR = bia[Jg2];
    const float baR   = ba[a_id];
    const float WaoR  = Wao[a_id];
    const float baoR  = bao[0];
    const float wax0  = Wa[(size_t)a_id * 515 + 512];
    const float wax1  = Wa[(size_t)a_id * 515 + 513];
    const float wax2  = Wa[(size_t)a_id * 515 + 514];

    __shared__ __align__(16) float hprev_p[4 * 132];   // 4 chunks of 132 (pad)
    __shared__ float Mh[4][128];                       // M ring, node&3
    __shared__ float cring[4][32];                     // c_node ring
    __shared__ float harcl[4][32];
    __shared__ float carcl[4][32];
    __shared__ float logit_l[4];
    __shared__ float WaS[64][33];                      // Wa rows, own 32 dims
    __shared__ float xpl[2][4][128];                   // parity-buffered x-proj
    __shared__ __align__(16) float x_s[4][256];
    __shared__ float xpart[4][4][128];

    for (int l2 = tid; l2 < 4 * 132; l2 += THR) hprev_p[l2] = 0.f;
    for (int l2 = tid; l2 < 512; l2 += THR) Mh[l2 >> 7][l2 & 127] = 0.f;
    if (tid < 128) cring[tid >> 5][tid & 31] = 0.f;
    for (int l2 = tid; l2 < 2048; l2 += THR)
        WaS[l2 >> 5][l2 & 31] = Wa[(size_t)(l2 >> 5) * 515 + bl * 32 + (l2 & 31)];
    __syncthreads();

// issue the edge-row load (threads tid<256: arc = tid>>6, chunk = tid&63)
#define XLOAD(nn, XV) do {                                                    \
        if (tid < 256) {                                                      \
            const int a4_ = tid >> 6, c4_ = tid & 63;                         \
            int row_;                                                         \
            if (dir == 0) row_ = (nn) * 4 + a4_;                              \
            else { row_ = ((nn) + 1 + a4_) * 4 + a4_;                         \
                   if (row_ > kE - 1) row_ = kE - 1; }                        \
            XV = *(const float4*)(edges + (size_t)row_ * kF + 4 * c4_);       \
        }                                                                     \
    } while (0)

// xproj for a node into xpl[BUF]; Wih streamed from global (L2-resident)
#define XFIN(XV, BUF, ZXOUT) do {                                             \
        if (tid < 256) *(float4*)(&x_s[tid >> 6][(tid & 63) * 4]) = XV;       \
        __syncthreads();                                                      \
        float p0_ = 0.f, p1_ = 0.f, p2_ = 0.f, p3_ = 0.f;                     \
        _Pragma("unroll")                                                     \
        for (int k4_ = 0; k4_ < 16; k4_++) {                                  \
            float4 wv_ = *(const float4*)(wihr + k4_ * 4);                    \
            float4 a0_ = *(const float4*)&x_s[0][d_gx * 64 + k4_ * 4];        \
            float4 a1_ = *(const float4*)&x_s[1][d_gx * 64 + k4_ * 4];        \
            float4 a2_ = *(const float4*)&x_s[2][d_gx * 64 + k4_ * 4];        \
            float4 a3_ = *(const float4*)&x_s[3][d_gx * 64 + k4_ * 4];        \
            p0_ += wv_.x*a0_.x + wv_.y*a0_.y + wv_.z*a0_.z + wv_.w*a0_.w;     \
            p1_ += wv_.x*a1_.x + wv_.y*a1_.y + wv_.z*a1_.z + wv_.w*a1_.w;     \
            p2_ += wv_.x*a2_.x + wv_.y*a2_.y + wv_.z*a2_.z + wv_.w*a2_.w;     \
            p3_ += wv_.x*a3_.x + wv_.y*a3_.y + wv_.z*a3_.z + wv_.w*a3_.w;     \
        }                                                                     \
        xpart[d_gx][0][jlx] = p0_; xpart[d_gx][1][jlx] = p1_;                 \
        xpart[d_gx][2][jlx] = p2_; xpart[d_gx][3][jlx] = p3_;                 \
        __syncthreads();                                                      \
        xpl[BUF][d_gx][jlx] = biasR + xpart[0][d_gx][jlx] + xpart[1][d_gx][jlx] \
                                    + xpart[2][d_gx][jlx] + xpart[3][d_gx][jlx]; \
        ZXOUT = baR + wax0 * x_s[d_gx][0] + wax1 * x_s[d_gx][1]               \
                    + wax2 * x_s[d_gx][2];                                    \
    } while (0)

    const int i0 = dir ? kN - 1 : 0;
    float zxv, zx_n;
    {
        float4 xv0;
        XLOAD(i0, xv0);
        XFIN(xv0, 0, zxv);
    }
    __syncthreads();   // xpl[0] visible before t=0 cell

    for (int t = 0; t < kN; t++) {
        const int i = dir ? kN - 1 - t : t;
        const int par = t & 1;
        const unsigned stamp = (unsigned)(t + 1);
        const int r = dir * 2 + par;

        // ---- prefetch next node's edge row ----
        float4 xv_n;
        {
            const int nn = (t + 1 < kN) ? (dir ? i - 1 : i + 1) : i;
            XLOAD(nn, xv_n);
        }

        // ---- A: M[iprev] = hprev . Whh^T (own 128 rows) ----
        float acc = 0.f;
        {
            const float* hp = &hprev_p[ks * 132];
            #pragma unroll
            for (int kk = 0; kk < 128; kk += 4) {
                float4 hv = *(const float4*)(hp + kk);
                acc += w[kk] * hv.x + w[kk+1] * hv.y + w[kk+2] * hv.z + w[kk+3] * hv.w;
            }
        }
        acc += __shfl_xor(acc, 1);
        acc += __shfl_xor(acc, 2);
        const int iprev = dir ? i + 1 : i - 1;
        if (ks == 0) Mh[iprev & 3][jl] = acc;

        // ---- XFIN for the NEXT node into the other parity buffer.
        //      Its barriers also order Mh-write (A) before cell reads. ----
        XFIN(xv_n, par ^ 1, zx_n);

        // ---- B: cell (lanes jlx<32 of each d-group) + publish; z partial ----
        const int pp = dir ? i + 1 + d_gx : i - 1 - d_gx;
        const bool v3 = dir ? (pp < kN) : (pp >= 0);
        float zp = 0.f;
        if (jlx < 32) {
            const int s3 = jlx;
            float gi = xpl[par][d_gx][s3]      + Mh[pp & 3][s3];
            float gf = xpl[par][d_gx][32 + s3] + Mh[pp & 3][32 + s3];
            float gg = xpl[par][d_gx][64 + s3] + Mh[pp & 3][64 + s3];
            float go = xpl[par][d_gx][96 + s3] + Mh[pp & 3][96 + s3];
            float cp = cring[pp & 3][s3];
            float c = sigm(gf) * cp + sigm(gi) * tanhf(gg);
            float h = sigm(go) * tanhf(c);
            float hm = v3 ? h : 0.f, cm = v3 ? c : 0.f;
            harcl[d_gx][s3] = hm; carcl[d_gx][s3] = cm;
            arc[((size_t)i * 4 + d_gx) * kH + bl * 32 + s3] = __float2bfloat16(hm);
            st_pair(hpay + ((size_t)(r * 4 + d_gx) << 9) + bl * 32 + s3, hm, stamp);
        }
        const bool zact = (jlx < 64);
        if (zact) {   // same wave as the cell writers -> no barrier needed
            #pragma unroll
            for (int ss = 0; ss < 32; ss++) zp += WaS[a_id][ss] * harcl[d_gx][ss];
            st_pair(zpay + ((size_t)(r * BPD + bl) << 8) + (d_gx << 6) + a_id, zp, stamp);
        }

        // ---- E: resolve (NO barrier since publish; own slots from regs/LDS) --
        ull zv_[BPD];
        const ull* zb = zpay + ((size_t)(r * BPD) << 8) + (d_gx << 6) + a_id;
        if (zact) {
            #pragma unroll
            for (int bb = 0; bb < BPD; bb++)
                zv_[bb] = (bb == bl) ? (((ull)stamp << 32) | (ull)__float_as_uint(zp))
                                     : ld_pair(zb + ((size_t)bb << 8));
        }
        const bool hown = ((tid >> 5) == bl);
        ull hv_[4];
        const ull* hb = hpay + ((size_t)(r * 4) << 9) + tid;
        if (!hown) {
            #pragma unroll
            for (int d = 0; d < 4; d++) hv_[d] = ld_pair(hb + (d << 9));
        }

        if (zact) {
            for (;;) {
                bool ok = true;
                #pragma unroll
                for (int bb = 0; bb < BPD; bb++)
                    ok &= ((unsigned)(zv_[bb] >> 32) == stamp);
                if (ok) break;
                #pragma unroll
                for (int bb = 0; bb < BPD; bb++)
                    if (bb != bl && (unsigned)(zv_[bb] >> 32) != stamp)
                        zv_[bb] = ld_pair(zb + ((size_t)bb << 8));
            }
            float zsum = 0.f;
            #pragma unroll
            for (int bb = 0; bb < BPD; bb++) zsum += __uint_as_float((unsigned)zv_[bb]);
            float lv = WaoR * fmaxf(zsum + zxv, 0.f);
            #pragma unroll
            for (int o2 = 1; o2 < 64; o2 <<= 1) lv += __shfl_xor(lv, o2);
            if (jlx == 0) logit_l[d_gx] = v3 ? tanhf(lv + baoR) : -1e9f;
        }
        if (!hown) {
            for (;;) {
                bool ok = true;
                #pragma unroll
                for (int d = 0; d < 4; d++)
                    ok &= ((unsigned)(hv_[d] >> 32) == stamp);
                if (ok) break;
                #pragma unroll
                for (int d = 0; d < 4; d++)
                    if ((unsigned)(hv_[d] >> 32) != stamp)
                        hv_[d] = ld_pair(hb + (d << 9));
            }
        }
        __syncthreads();   // logits + harcl/carcl visible block-wide

        // ---- combine: softmax -> h_node (one dim per thread), c_node ----
        float l0 = logit_l[0], l1 = logit_l[1], l2 = logit_l[2], l3 = logit_l[3];
        float mx = fmaxf(fmaxf(l0, l1), fmaxf(l2, l3));
        float e0 = __expf(l0 - mx), e1 = __expf(l1 - mx);
        float e2 = __expf(l2 - mx), e3 = __expf(l3 - mx);
        float inv = 1.f / (e0 + e1 + e2 + e3);
        float wg[4] = { e0 * inv, e1 * inv, e2 * inv, e3 * inv };

        float hn = 0.f;
        #pragma unroll
        for (int d = 0; d < 4; d++) {
            float hd = hown ? harcl[d][tid & 31]
                            : __uint_as_float((unsigned)hv_[d]);
            hn += wg[d] * hd;
        }
        hprev_p[(tid >> 7) * 132 + (tid & 127)] = hn;
        if (tid < 32) {
            float cn = wg[0] * carcl[0][tid] + wg[1] * carcl[1][tid]
                     + wg[2] * carcl[2][tid] + wg[3] * carcl[3][tid];
            cring[i & 3][tid] = cn;
        }
        __syncthreads();

        zxv = zx_n;
    }
#undef XLOAD
#undef XFIN
}

// ---------------------------------------------------------------------------
// decoder: out[e] += sum_l Wdo[l] * relu(bd[l] + sum_k Wd[l,k] feat[e,k])
// ---------------------------------------------------------------------------
__global__ __launch_bounds__(256) void k_dec(
    const __hip_bfloat16* __restrict__ arc_f, const __hip_bfloat16* __restrict__ arc_b,
    const float* __restrict__ Wd, const float* __restrict__ bd,
    const float* __restrict__ Wdo, float* __restrict__ out) {
    const int e0 = blockIdx.x * 128;
    const int l0 = blockIdx.y * 128;
    __shared__ __align__(16) float As[8][128];
    __shared__ __align__(16) float Bs[8][128];
    const int tid = threadIdx.x;
    const int tx = tid & 15, ty = tid >> 4;
    const int lr = tid & 127, kq = tid >> 7;

    const int e = e0 + lr;
    const int j = e >> 2, d = e & 3;
    const int jb = j - 1 - d;
    const __hip_bfloat16* frow  = arc_f + (size_t)e * kH;
    const __hip_bfloat16* brow2 = (jb >= 0) ? (arc_b + ((size_t)jb * 4 + d) * kH) : nullptr;
    const float* wrow = Wd + (size_t)(l0 + lr) * (2 * kH);

    float acc[8][8] = {};
    for (int k0 = 0; k0 < 2 * kH; k0 += 8) {
        const int kk = k0 + kq * 4;
        float4 av4;
        if (kk < kH) av4 = ld_bf4(frow + kk);
        else if (brow2) av4 = ld_bf4(brow2 + (kk - kH));
        else av4 = make_float4(0.f, 0.f, 0.f, 0.f);
        float4 bv4 = *(const float4*)(wrow + kk);
        __syncthreads();
        As[kq*4+0][lr] = av4.x; As[kq*4+1][lr] = av4.y;
        As[kq*4+2][lr] = av4.z; As[kq*4+3][lr] = av4.w;
        Bs[kq*4+0][lr] = bv4.x; Bs[kq*4+1][lr] = bv4.y;
        Bs[kq*4+2][lr] = bv4.z; Bs[kq*4+3][lr] = bv4.w;
        __syncthreads();
        #pragma unroll
        for (int kt = 0; kt < 8; kt++) {
            __align__(16) float a0[8], b0[8];
            *(float4*)&a0[0] = *(const float4*)&As[kt][ty*8];
            *(float4*)&a0[4] = *(const float4*)&As[kt][ty*8+4];
            *(float4*)&b0[0] = *(const float4*)&Bs[kt][tx*8];
            *(float4*)&b0[4] = *(const float4*)&Bs[kt][tx*8+4];
            #pragma unroll
            for (int mi = 0; mi < 8; mi++)
                #pragma unroll
                for (int ni = 0; ni < 8; ni++)
                    acc[mi][ni] += a0[mi] * b0[ni];
        }
    }
    #pragma unroll
    for (int mi = 0; mi < 8; mi++) {
        float sacc = 0.f;
        #pragma unroll
        for (int ni = 0; ni < 8; ni++) {
            int l = l0 + tx * 8 + ni;
            sacc += Wdo[l] * fmaxf(acc[mi][ni] + bd[l], 0.f);
        }
        sacc += __shfl_xor(sacc, 1);
        sacc += __shfl_xor(sacc, 2);
        sacc += __shfl_xor(sacc, 4);
        sacc += __shfl_xor(sacc, 8);
        if (tx == 0) atomicAdd(out + e0 + ty * 8 + mi, sacc);
    }
}

// ---------------------------------------------------------------------------
extern "C" void kernel_launch(void* const* d_in, const int* in_sizes, int n_in,
                              void* d_out, int out_size, void* d_ws, size_t ws_size,
                              hipStream_t stream) {
    const float* edges = (const float*)d_in[0];
    const float* Wih_f = (const float*)d_in[1];
    const float* Whh_f = (const float*)d_in[2];
    const float* b_f   = (const float*)d_in[3];
    const float* Wih_b = (const float*)d_in[4];
    const float* Whh_b = (const float*)d_in[5];
    const float* b_b   = (const float*)d_in[6];
    const float* Wa    = (const float*)d_in[7];
    const float* ba    = (const float*)d_in[8];
    const float* Wao   = (const float*)d_in[9];
    const float* bao   = (const float*)d_in[10];
    const float* Wd    = (const float*)d_in[11];
    const float* bd    = (const float*)d_in[12];
    const float* Wdo   = (const float*)d_in[13];
    const float* bdo   = (const float*)d_in[14];
    float* out = (float*)d_out;

    char* ws = (char*)d_ws;
    size_t off = 0;
    __hip_bfloat16* arc_f = (__hip_bfloat16*)(ws + off); off += (size_t)kE * kH * 2;  // 32 MB
    __hip_bfloat16* arc_b = (__hip_bfloat16*)(ws + off); off += (size_t)kE * kH * 2;  // 32 MB
    ull* hpay = (ull*)(ws + off); off += (size_t)2 * 2 * 4 * kH * 8;                  // 64 KB
    ull* zpay = (ull*)(ws + off); off += (size_t)2 * 2 * BPD * 256 * 8;               // 128 KB
    int* claims = (int*)(ws + off); off += 64;

    if (ws_size < off) {
        hipLaunchKernelGGL(k_zero, dim3((kE + 255) / 256), dim3(256), 0, stream, out);
        return;
    }

    hipLaunchKernelGGL(k_init, dim3(128), dim3(256), 0, stream,
                       out, bdo, hpay, zpay, claims);
    hipLaunchKernelGGL(k_recur, dim3(512), dim3(THR), 0, stream,
                       edges, Wih_f, Whh_f, b_f, Wih_b, Whh_b, b_b,
                       Wa, ba, Wao, bao, arc_f, arc_b, hpay, zpay, claims);
    hipLaunchKernelGGL(k_dec, dim3(kE / 128, kL / 128), dim3(256), 0, stream,
                       arc_f, arc_b, Wd, bd, Wdo, out);
}

// Round 10
// 65356.116 us; speedup vs baseline: 1.4031x; 1.4031x over previous
//
#include <hip/hip_runtime.h>
#include <hip/hip_bf16.h>

// Problem constants
constexpr int kN = 8192;
constexpr int kF = 256;
constexpr int kH = 512;
constexpr int kL = 512;
constexpr int kE = kN * 4;           // 32768 edges

using ull = unsigned long long;

__device__ __forceinline__ float sigm(float x) { return 1.f / (1.f + __expf(-x)); }

__device__ __forceinline__ float4 ld_bf4(const __hip_bfloat16* p) {
    uint2 u = *(const uint2*)p;
    float4 r;
    r.x = __uint_as_float(u.x << 16);
    r.y = __uint_as_float(u.x & 0xffff0000u);
    r.z = __uint_as_float(u.y << 16);
    r.w = __uint_as_float(u.y & 0xffff0000u);
    return r;
}

// stamped 8-byte pair: low = float bits, high = stamp (publish step + 1)
// relaxed agent-scope atomics: the only encoding that both pipelines and is
// safe (volatile -> serialized vmcnt(0) [r6]; cache-op tricks -> fault [r8]).
__device__ __forceinline__ void st_pair(ull* p, float v, unsigned stamp) {
    ull u = ((ull)stamp << 32) | (ull)__float_as_uint(v);
    __hip_atomic_store(p, u, __ATOMIC_RELAXED, __HIP_MEMORY_SCOPE_AGENT);
}
__device__ __forceinline__ ull ld_pair(const ull* p) {
    return __hip_atomic_load(p, __ATOMIC_RELAXED, __HIP_MEMORY_SCOPE_AGENT);
}

// ---------------------------------------------------------------------------
__global__ void k_init(float* __restrict__ out, const float* __restrict__ bdo,
                       ull* __restrict__ hpay, ull* __restrict__ zpay,
                       int* __restrict__ claims) {
    int idx = blockIdx.x * 256 + threadIdx.x;
    if (idx < kE) out[idx] = bdo[0];
    if (idx < 2 * 2 * 4 * kH) hpay[idx] = 0ull;
    if (idx < 2 * 2 * 32 * 256) zpay[idx] = 0ull;
    if (idx < 2) claims[idx] = 0;
}

__global__ void k_zero(float* __restrict__ out) {
    int idx = blockIdx.x * 256 + threadIdx.x;
    if (idx < kE) out[idx] = 0.f;
}

// ---------------------------------------------------------------------------
// Recurrent kernel: round-5 geometry (32 blocks/dir x 256 thr, XCD-claimed),
// round-9 ordering: XFIN(next) BEFORE the cell, so publish -> resolve has NO
// intervening barrier (no vmcnt(0) drain on our own MALL store ACKs), and
// own-block contributions come from registers/LDS (no self round trip).
// Block b owns h-dims [b*16, b*16+16) -> 64 gate rows (Whh slice in VGPRs).
// ---------------------------------------------------------------------------
__global__ __launch_bounds__(256, 1) void k_recur(
    const float* __restrict__ edges,
    const float* __restrict__ Wih_f, const float* __restrict__ Whh_f, const float* __restrict__ b_f,
    const float* __restrict__ Wih_b, const float* __restrict__ Whh_b, const float* __restrict__ b_b,
    const float* __restrict__ Wa, const float* __restrict__ ba,
    const float* __restrict__ Wao, const float* __restrict__ bao,
    __hip_bfloat16* __restrict__ arc_f, __hip_bfloat16* __restrict__ arc_b,
    ull* __restrict__ hpay, ull* __restrict__ zpay, int* __restrict__ claims) {

    // ---- XCD-affine slot claim ----
    __shared__ int s_slot;
    if (threadIdx.x == 0) {
        unsigned xcc = (unsigned)__builtin_amdgcn_s_getreg((31 << 11) | (0 << 6) | 20) & 15u;
        int slot = -1;
        if (xcc <= 1) {
            int c = atomicAdd(&claims[xcc], 1);
            if (c < 32) slot = (int)xcc * 32 + c;
        } else {
            for (int sl = 0; sl < 64; sl++) __builtin_amdgcn_s_sleep(64);
            for (int dd = 0; dd < 2 && slot < 0; dd++) {
                if (__hip_atomic_load(&claims[dd], __ATOMIC_RELAXED,
                                      __HIP_MEMORY_SCOPE_AGENT) < 32) {
                    int c = atomicAdd(&claims[dd], 1);
                    if (c < 32) slot = dd * 32 + c;
                }
            }
        }
        s_slot = slot;
    }
    __syncthreads();
    const int slot = s_slot;
    if (slot < 0) return;
    const int dir = slot >> 5;
    const int b   = slot & 31;

    const float* __restrict__ Whh = dir ? Whh_b : Whh_f;
    const float* __restrict__ Wih = dir ? Wih_b : Wih_f;
    const float* __restrict__ bia = dir ? b_b  : b_f;
    __hip_bfloat16* __restrict__ arc = dir ? arc_b : arc_f;
    const int tid = threadIdx.x;

    // matvec roles: 64 gate rows x 4-way K split
    const int jl = tid >> 2, ks = tid & 3;
    const int Jg = (jl >> 4) * kH + b * 16 + (jl & 15);
    // gate / xproj / z roles: wave = arc, lane = gate row (or attention unit)
    const int d_g = tid >> 6, jl2 = tid & 63;
    const int Jg2 = (jl2 >> 4) * kH + b * 16 + (jl2 & 15);
    const int a_id = jl2;

    float w[128];
    {
        const float* wr = Whh + (size_t)Jg * kH + ks * 128;
        #pragma unroll
        for (int kk = 0; kk < 128; kk++) w[kk] = wr[kk];
    }
    float wih[64];
    {
        const float* wr = Wih + (size_t)Jg2 * kF + d_g * 64;
        #pragma unroll
        for (int kk = 0; kk < 64; kk++) wih[kk] = wr[kk];
    }
    const float biasR = bia[Jg2];
    const float baR   = ba[a_id];
    const float WaoR  = Wao[a_id];
    const float baoR  = bao[0];
    const float wax0  = Wa[(size_t)a_id * 515 + 512];
    const float wax1  = Wa[(size_t)a_id * 515 + 513];
    const float wax2  = Wa[(size_t)a_id * 515 + 514];

    // hprev padded: 4 chunks of 132 floats (banks offset 4 per chunk -> no conflict)
    __shared__ __align__(16) float hprev_p[4 * 132];
    __shared__ float Mh[4][64];
    __shared__ float cring[4][16];
    __shared__ float harcl[4][16];
    __shared__ float carcl[4][16];
    __shared__ float logit_l[4];
    __shared__ float WaS[64][17];
    __shared__ float xpl[2][4][64];      // parity-buffered gate-x projection
    __shared__ __align__(16) float x_s[4][256];
    __shared__ float xpart[4][4][64];

    for (int l2 = tid; l2 < 4 * 132; l2 += 256) hprev_p[l2] = 0.f;
    Mh[tid >> 6][tid & 63] = 0.f;
    if (tid < 64) cring[tid >> 4][tid & 15] = 0.f;
    for (int l2 = tid; l2 < 1024; l2 += 256)
        WaS[l2 >> 4][l2 & 15] = Wa[(size_t)(l2 >> 4) * 515 + b * 16 + (l2 & 15)];
    __syncthreads();

// issue the edge-row load for node nn (block-uniform)
#define XLOAD(nn, XV) do {                                                    \
        int row_;                                                             \
        if (dir == 0) row_ = (nn) * 4 + d_g;                                  \
        else { row_ = ((nn) + 1 + d_g) * 4 + d_g;                             \
               if (row_ > kE - 1) row_ = kE - 1; }                            \
        XV = *(const float4*)(edges + (size_t)row_ * kF + 4 * jl2);           \
    } while (0)

// xproj from a prefetched edge vector into xpl[BUF]; returns zx of that node
#define XFIN(XV, BUF, ZXOUT) do {                                             \
        *(float4*)(&x_s[d_g][4 * jl2]) = XV;                                  \
        __syncthreads();                                                      \
        float p0_ = 0.f, p1_ = 0.f, p2_ = 0.f, p3_ = 0.f;                     \
        _Pragma("unroll")                                                     \
        for (int k4_ = 0; k4_ < 16; k4_++) {                                  \
            float4 a0_ = *(const float4*)&x_s[0][d_g * 64 + k4_ * 4];         \
            float4 a1_ = *(const float4*)&x_s[1][d_g * 64 + k4_ * 4];         \
            float4 a2_ = *(const float4*)&x_s[2][d_g * 64 + k4_ * 4];         \
            float4 a3_ = *(const float4*)&x_s[3][d_g * 64 + k4_ * 4];         \
            float w0_ = wih[k4_*4], w1_ = wih[k4_*4+1];                       \
            float w2_ = wih[k4_*4+2], w3_ = wih[k4_*4+3];                     \
            p0_ += w0_*a0_.x + w1_*a0_.y + w2_*a0_.z + w3_*a0_.w;             \
            p1_ += w0_*a1_.x + w1_*a1_.y + w2_*a1_.z + w3_*a1_.w;             \
            p2_ += w0_*a2_.x + w1_*a2_.y + w2_*a2_.z + w3_*a2_.w;             \
            p3_ += w0_*a3_.x + w1_*a3_.y + w2_*a3_.z + w3_*a3_.w;             \
        }                                                                     \
        xpart[d_g][0][jl2] = p0_; xpart[d_g][1][jl2] = p1_;                   \
        xpart[d_g][2][jl2] = p2_; xpart[d_g][3][jl2] = p3_;                   \
        __syncthreads();                                                      \
        xpl[BUF][d_g][jl2] = biasR + xpart[0][d_g][jl2] + xpart[1][d_g][jl2]  \
                                   + xpart[2][d_g][jl2] + xpart[3][d_g][jl2]; \
        ZXOUT = baR + wax0 * x_s[d_g][0] + wax1 * x_s[d_g][1]                 \
                    + wax2 * x_s[d_g][2];                                     \
    } while (0)

    const int i0 = dir ? kN - 1 : 0;
    float zxv, zx_n;
    {
        float4 xv0;
        XLOAD(i0, xv0);
        XFIN(xv0, 0, zxv);
    }
    __syncthreads();   // xpl[0] visible before t=0 cell

    for (int t = 0; t < kN; t++) {
        const int i = dir ? kN - 1 - t : t;
        const unsigned stamp = (unsigned)(t + 1);
        const int par = t & 1;
        const int r = dir * 2 + par;

        // ---- prefetch next node's edge row ----
        float4 xv_n;
        {
            const int nn = (t + 1 < kN) ? (dir ? i - 1 : i + 1) : i;
            XLOAD(nn, xv_n);
        }

        // ---- A: M[iprev] = hprev . Whh^T (own 64 rows) ----
        float acc = 0.f;
        {
            const float* hp = &hprev_p[ks * 132];
            #pragma unroll
            for (int kk = 0; kk < 128; kk += 4) {
                float4 hv = *(const float4*)(hp + kk);
                acc += w[kk] * hv.x + w[kk+1] * hv.y + w[kk+2] * hv.z + w[kk+3] * hv.w;
            }
        }
        acc += __shfl_xor(acc, 1);
        acc += __shfl_xor(acc, 2);
        const int iprev = dir ? i + 1 : i - 1;
        if (ks == 0) Mh[iprev & 3][jl] = acc;

        // ---- XFIN for the NEXT node (barriers order Mh-write before cell,
        //      and sit BEFORE publish -> no post-publish drain) ----
        XFIN(xv_n, par ^ 1, zx_n);

        // ---- B: per-wave cell (wave = arc) + publish h,z; NO barrier ----
        const int pp = dir ? i + 1 + d_g : i - 1 - d_g;
        const bool v3 = dir ? (pp < kN) : (pp >= 0);
        if (jl2 < 16) {
            const int s3 = jl2;
            float gi = xpl[par][d_g][s3]      + Mh[pp & 3][s3];
            float gf = xpl[par][d_g][16 + s3] + Mh[pp & 3][16 + s3];
            float gg = xpl[par][d_g][32 + s3] + Mh[pp & 3][32 + s3];
            float go = xpl[par][d_g][48 + s3] + Mh[pp & 3][48 + s3];
            float cp = cring[pp & 3][s3];
            float c = sigm(gf) * cp + sigm(gi) * tanhf(gg);
            float h = sigm(go) * tanhf(c);
            float hm = v3 ? h : 0.f, cm = v3 ? c : 0.f;
            harcl[d_g][s3] = hm; carcl[d_g][s3] = cm;
            arc[((size_t)i * 4 + d_g) * kH + b * 16 + s3] = __float2bfloat16(hm);
            st_pair(hpay + (((size_t)r * 4 + d_g) << 9) + b * 16 + s3, hm, stamp);
        }
        float zp = 0.f;
        {   // z partial over own 16 h-dims (intra-wave harcl dep, no barrier)
            #pragma unroll
            for (int ss = 0; ss < 16; ss++) zp += WaS[a_id][ss] * harcl[d_g][ss];
            st_pair(zpay + (((size_t)r * 32 + b) << 8) + tid, zp, stamp);
        }

        // ---- E: resolve IMMEDIATELY (own slots from reg/LDS, no self-RTT) ----
        const ull* zb = zpay + (((size_t)r * 32) << 8) + tid;
        ull zv_[32];
        #pragma unroll
        for (int bb = 0; bb < 32; bb++)
            zv_[bb] = (bb == b) ? (((ull)stamp << 32) | (ull)__float_as_uint(zp))
                                : ld_pair(zb + ((size_t)bb << 8));
        const int g0 = 2 * tid, g1 = 2 * tid + 1;
        const bool hown = ((g0 >> 4) == b);
        const ull* hb = hpay + (((size_t)r * 4) << 9);
        ull hv_[8];
        if (!hown) {
            #pragma unroll
            for (int dd = 0; dd < 4; dd++) {
                hv_[2*dd]   = ld_pair(hb + (dd << 9) + g0);
                hv_[2*dd+1] = ld_pair(hb + (dd << 9) + g1);
            }
        }

        // resolve z: batched sweeps
        for (;;) {
            bool ok = true;
            #pragma unroll
            for (int bb = 0; bb < 32; bb++)
                ok &= ((unsigned)(zv_[bb] >> 32) == stamp);
            if (ok) break;
            #pragma unroll
            for (int bb = 0; bb < 32; bb++)
                if (bb != b && (unsigned)(zv_[bb] >> 32) != stamp)
                    zv_[bb] = ld_pair(zb + ((size_t)bb << 8));
        }
        float zsum = 0.f;
        #pragma unroll
        for (int bb = 0; bb < 32; bb++) zsum += __uint_as_float((unsigned)zv_[bb]);
        float lv = WaoR * fmaxf(zsum + zxv, 0.f);
        #pragma unroll
        for (int o2 = 1; o2 < 64; o2 <<= 1) lv += __shfl_xor(lv, o2);
        if (jl2 == 0) logit_l[d_g] = v3 ? tanhf(lv + baoR) : -1e9f;

        // resolve h: batched sweeps
        if (!hown) {
            for (;;) {
                bool ok = true;
                #pragma unroll
                for (int q = 0; q < 8; q++)
                    ok &= ((unsigned)(hv_[q] >> 32) == stamp);
                if (ok) break;
                #pragma unroll
                for (int dd = 0; dd < 4; dd++) {
                    if ((unsigned)(hv_[2*dd]   >> 32) != stamp) hv_[2*dd]   = ld_pair(hb + (dd << 9) + g0);
                    if ((unsigned)(hv_[2*dd+1] >> 32) != stamp) hv_[2*dd+1] = ld_pair(hb + (dd << 9) + g1);
                }
            }
        }
        __syncthreads();   // logits + harcl/carcl visible block-wide (post-resolve)

        // ---- combine: softmax -> h_node, c_node ----
        float l0 = logit_l[0], l1 = logit_l[1], l2 = logit_l[2], l3 = logit_l[3];
        float mx = fmaxf(fmaxf(l0, l1), fmaxf(l2, l3));
        float e0 = __expf(l0 - mx), e1 = __expf(l1 - mx);
        float e2 = __expf(l2 - mx), e3 = __expf(l3 - mx);
        float inv = 1.f / (e0 + e1 + e2 + e3);
        float wg[4] = { e0 * inv, e1 * inv, e2 * inv, e3 * inv };

        float hn0 = 0.f, hn1 = 0.f;
        #pragma unroll
        for (int dd = 0; dd < 4; dd++) {
            float a0 = hown ? harcl[dd][g0 & 15] : __uint_as_float((unsigned)hv_[2*dd]);
            float a1 = hown ? harcl[dd][g1 & 15] : __uint_as_float((unsigned)hv_[2*dd+1]);
            hn0 += wg[dd] * a0; hn1 += wg[dd] * a1;
        }
        {
            const int ch = g0 >> 7, wi = g0 & 127;
            hprev_p[ch * 132 + wi]     = hn0;
            hprev_p[ch * 132 + wi + 1] = hn1;
        }
        if (tid < 16) {
            float cn = wg[0] * carcl[0][tid] + wg[1] * carcl[1][tid]
                     + wg[2] * carcl[2][tid] + wg[3] * carcl[3][tid];
            cring[i & 3][tid] = cn;
        }
        __syncthreads();

        zxv = zx_n;
    }
#undef XLOAD
#undef XFIN
}

// ---------------------------------------------------------------------------
// decoder: out[e] += sum_l Wdo[l] * relu(bd[l] + sum_k Wd[l,k] feat[e,k])
// ---------------------------------------------------------------------------
__global__ __launch_bounds__(256) void k_dec(
    const __hip_bfloat16* __restrict__ arc_f, const __hip_bfloat16* __restrict__ arc_b,
    const float* __restrict__ Wd, const float* __restrict__ bd,
    const float* __restrict__ Wdo, float* __restrict__ out) {
    const int e0 = blockIdx.x * 128;
    const int l0 = blockIdx.y * 128;
    __shared__ __align__(16) float As[8][128];
    __shared__ __align__(16) float Bs[8][128];
    const int tid = threadIdx.x;
    const int tx = tid & 15, ty = tid >> 4;
    const int lr = tid & 127, kq = tid >> 7;

    const int e = e0 + lr;
    const int j = e >> 2, d = e & 3;
    const int jb = j - 1 - d;
    const __hip_bfloat16* frow  = arc_f + (size_t)e * kH;
    const __hip_bfloat16* brow2 = (jb >= 0) ? (arc_b + ((size_t)jb * 4 + d) * kH) : nullptr;
    const float* wrow = Wd + (size_t)(l0 + lr) * (2 * kH);

    float acc[8][8] = {};
    for (int k0 = 0; k0 < 2 * kH; k0 += 8) {
        const int kk = k0 + kq * 4;
        float4 av4;
        if (kk < kH) av4 = ld_bf4(frow + kk);
        else if (brow2) av4 = ld_bf4(brow2 + (kk - kH));
        else av4 = make_float4(0.f, 0.f, 0.f, 0.f);
        float4 bv4 = *(const float4*)(wrow + kk);
        __syncthreads();
        As[kq*4+0][lr] = av4.x; As[kq*4+1][lr] = av4.y;
        As[kq*4+2][lr] = av4.z; As[kq*4+3][lr] = av4.w;
        Bs[kq*4+0][lr] = bv4.x; Bs[kq*4+1][lr] = bv4.y;
        Bs[kq*4+2][lr] = bv4.z; Bs[kq*4+3][lr] = bv4.w;
        __syncthreads();
        #pragma unroll
        for (int kt = 0; kt < 8; kt++) {
            __align__(16) float a0[8], b0[8];
            *(float4*)&a0[0] = *(const float4*)&As[kt][ty*8];
            *(float4*)&a0[4] = *(const float4*)&As[kt][ty*8+4];
            *(float4*)&b0[0] = *(const float4*)&Bs[kt][tx*8];
            *(float4*)&b0[4] = *(const float4*)&Bs[kt][tx*8+4];
            #pragma unroll
            for (int mi = 0; mi < 8; mi++)
                #pragma unroll
                for (int ni = 0; ni < 8; ni++)
                    acc[mi][ni] += a0[mi] * b0[ni];
        }
    }
    #pragma unroll
    for (int mi = 0; mi < 8; mi++) {
        float sacc = 0.f;
        #pragma unroll
        for (int ni = 0; ni < 8; ni++) {
            int l = l0 + tx * 8 + ni;
            sacc += Wdo[l] * fmaxf(acc[mi][ni] + bd[l], 0.f);
        }
        sacc += __shfl_xor(sacc, 1);
        sacc += __shfl_xor(sacc, 2);
        sacc += __shfl_xor(sacc, 4);
        sacc += __shfl_xor(sacc, 8);
        if (tx == 0) atomicAdd(out + e0 + ty * 8 + mi, sacc);
    }
}

// ---------------------------------------------------------------------------
extern "C" void kernel_launch(void* const* d_in, const int* in_sizes, int n_in,
                              void* d_out, int out_size, void* d_ws, size_t ws_size,
                              hipStream_t stream) {
    const float* edges = (const float*)d_in[0];
    const float* Wih_f = (const float*)d_in[1];
    const float* Whh_f = (const float*)d_in[2];
    const float* b_f   = (const float*)d_in[3];
    const float* Wih_b = (const float*)d_in[4];
    const float* Whh_b = (const float*)d_in[5];
    const float* b_b   = (const float*)d_in[6];
    const float* Wa    = (const float*)d_in[7];
    const float* ba    = (const float*)d_in[8];
    const float* Wao   = (const float*)d_in[9];
    const float* bao   = (const float*)d_in[10];
    const float* Wd    = (const float*)d_in[11];
    const float* bd    = (const float*)d_in[12];
    const float* Wdo   = (const float*)d_in[13];
    const float* bdo   = (const float*)d_in[14];
    float* out = (float*)d_out;

    char* ws = (char*)d_ws;
    size_t off = 0;
    __hip_bfloat16* arc_f = (__hip_bfloat16*)(ws + off); off += (size_t)kE * kH * 2;  // 32 MB
    __hip_bfloat16* arc_b = (__hip_bfloat16*)(ws + off); off += (size_t)kE * kH * 2;  // 32 MB
    ull* hpay = (ull*)(ws + off); off += (size_t)2 * 2 * 4 * kH * 8;                  // 64 KB
    ull* zpay = (ull*)(ws + off); off += (size_t)2 * 2 * 32 * 256 * 8;                // 256 KB
    int* claims = (int*)(ws + off); off += 64;

    if (ws_size < off) {
        hipLaunchKernelGGL(k_zero, dim3((kE + 255) / 256), dim3(256), 0, stream, out);
        return;
    }

    hipLaunchKernelGGL(k_init, dim3(128), dim3(256), 0, stream,
                       out, bdo, hpay, zpay, claims);
    hipLaunchKernelGGL(k_recur, dim3(512), dim3(256), 0, stream,
                       edges, Wih_f, Whh_f, b_f, Wih_b, Whh_b, b_b,
                       Wa, ba, Wao, bao, arc_f, arc_b, hpay, zpay, claims);
    hipLaunchKernelGGL(k_dec, dim3(kE / 128, kL / 128), dim3(256), 0, stream,
                       arc_f, arc_b, Wd, bd, Wdo, out);
}

// Round 11
// 45585.312 us; speedup vs baseline: 2.0117x; 1.4337x over previous
//
#include <hip/hip_runtime.h>
#include <hip/hip_bf16.h>

// Problem constants
constexpr int kN = 8192;
constexpr int kF = 256;
constexpr int kH = 512;
constexpr int kL = 512;
constexpr int kE = kN * 4;           // 32768 edges

using ull = unsigned long long;

__device__ __forceinline__ float sigm(float x) { return 1.f / (1.f + __expf(-x)); }

__device__ __forceinline__ float4 ld_bf4(const __hip_bfloat16* p) {
    uint2 u = *(const uint2*)p;
    float4 r;
    r.x = __uint_as_float(u.x << 16);
    r.y = __uint_as_float(u.x & 0xffff0000u);
    r.z = __uint_as_float(u.y << 16);
    r.w = __uint_as_float(u.y & 0xffff0000u);
    return r;
}

// stamped 8-byte pair: low = float bits, high = stamp (step+1)
// relaxed agent-scope atomics: the only encoding that both pipelines and is
// safe (volatile -> serialized vmcnt(0) [r6]; cache-op tricks -> fault [r8]).
__device__ __forceinline__ void st_pair(ull* p, float v, unsigned stamp) {
    ull u = ((ull)stamp << 32) | (ull)__float_as_uint(v);
    __hip_atomic_store(p, u, __ATOMIC_RELAXED, __HIP_MEMORY_SCOPE_AGENT);
}
__device__ __forceinline__ ull ld_raw(const ull* p) {
    return __hip_atomic_load(p, __ATOMIC_RELAXED, __HIP_MEMORY_SCOPE_AGENT);
}

// ---------------------------------------------------------------------------
__global__ void k_init(float* __restrict__ out, const float* __restrict__ bdo,
                       ull* __restrict__ hpay, ull* __restrict__ zpay,
                       int* __restrict__ claims) {
    int idx = blockIdx.x * 256 + threadIdx.x;
    if (idx < kE) out[idx] = bdo[0];
    if (idx < 2 * 2 * 4 * kH) hpay[idx] = 0ull;
    if (idx < 2 * 2 * 32 * 256) zpay[idx] = 0ull;
    if (idx < 2) claims[idx] = 0;
}

__global__ void k_zero(float* __restrict__ out) {
    int idx = blockIdx.x * 256 + threadIdx.x;
    if (idx < kE) out[idx] = 0.f;
}

// ---------------------------------------------------------------------------
// Recurrent kernel: round-5 structure verbatim (best measured: 45.9 ms).
// 512 candidate blocks; 32 working blocks/dir claimed by XCD (XCD0 fwd,
// XCD1 bwd, late fallback). Block b owns h-dims [b*16,b*16+16).
// Single delta vs round 5: s_sleep(2) backoff between retry sweeps to cut
// MALL spin congestion (retries can't accelerate arrival; they only congest).
// ---------------------------------------------------------------------------
__global__ __launch_bounds__(256, 1) void k_recur(
    const float* __restrict__ edges,
    const float* __restrict__ Wih_f, const float* __restrict__ Whh_f, const float* __restrict__ b_f,
    const float* __restrict__ Wih_b, const float* __restrict__ Whh_b, const float* __restrict__ b_b,
    const float* __restrict__ Wa, const float* __restrict__ ba,
    const float* __restrict__ Wao, const float* __restrict__ bao,
    __hip_bfloat16* __restrict__ arc_f, __hip_bfloat16* __restrict__ arc_b,
    ull* __restrict__ hpay, ull* __restrict__ zpay, int* __restrict__ claims) {

    // ---- XCD-affine slot claim ----
    __shared__ int s_slot;
    if (threadIdx.x == 0) {
        unsigned xcc = (unsigned)__builtin_amdgcn_s_getreg((31 << 11) | (0 << 6) | 20) & 15u;
        int slot = -1;
        if (xcc <= 1) {
            int c = atomicAdd(&claims[xcc], 1);
            if (c < 32) slot = (int)xcc * 32 + c;
        } else {
            for (int sl = 0; sl < 64; sl++) __builtin_amdgcn_s_sleep(64);
            for (int dd = 0; dd < 2 && slot < 0; dd++) {
                if (__hip_atomic_load(&claims[dd], __ATOMIC_RELAXED,
                                      __HIP_MEMORY_SCOPE_AGENT) < 32) {
                    int c = atomicAdd(&claims[dd], 1);
                    if (c < 32) slot = dd * 32 + c;
                }
            }
        }
        s_slot = slot;
    }
    __syncthreads();
    const int slot = s_slot;
    if (slot < 0) return;
    const int dir = slot >> 5;
    const int b   = slot & 31;

    const float* __restrict__ Whh = dir ? Whh_b : Whh_f;
    const float* __restrict__ Wih = dir ? Wih_b : Wih_f;
    const float* __restrict__ bia = dir ? b_b  : b_f;
    __hip_bfloat16* __restrict__ arc = dir ? arc_b : arc_f;
    const int tid = threadIdx.x;

    // matvec roles: 64 gate rows x 4-way K split
    const int jl = tid >> 2, ks = tid & 3;
    const int Jg = (jl >> 4) * kH + b * 16 + (jl & 15);
    // gate / xproj / z roles: wave = arc, lane = gate row (or attention unit)
    const int d_g = tid >> 6, jl2 = tid & 63;
    const int Jg2 = (jl2 >> 4) * kH + b * 16 + (jl2 & 15);
    const int a_id = jl2;

    float w[128];
    {
        const float* wr = Whh + (size_t)Jg * kH + ks * 128;
        #pragma unroll
        for (int kk = 0; kk < 128; kk++) w[kk] = wr[kk];
    }
    float wih[64];
    {
        const float* wr = Wih + (size_t)Jg2 * kF + d_g * 64;
        #pragma unroll
        for (int kk = 0; kk < 64; kk++) wih[kk] = wr[kk];
    }
    const float biasR = bia[Jg2];
    const float baR   = ba[a_id];
    const float WaoR  = Wao[a_id];
    const float baoR  = bao[0];
    const float wax0  = Wa[(size_t)a_id * 515 + 512];
    const float wax1  = Wa[(size_t)a_id * 515 + 513];
    const float wax2  = Wa[(size_t)a_id * 515 + 514];

    // hprev padded: 4 chunks of 132 floats (banks offset 4 per chunk -> no conflict)
    __shared__ __align__(16) float hprev_p[4 * 132];
    __shared__ float Mh[4][64];
    __shared__ float cring[4][16];
    __shared__ float gl[4][64];
    __shared__ float harcl[4][16];
    __shared__ float carcl[4][16];
    __shared__ float logit_l[4];
    __shared__ float WaS[64][17];
    __shared__ __align__(16) float x_s[4][256];
    __shared__ float xpart[4][4][64];

    for (int l2 = tid; l2 < 4 * 132; l2 += 256) hprev_p[l2] = 0.f;
    Mh[tid >> 6][tid & 63] = 0.f;
    if (tid < 64) cring[tid >> 4][tid & 15] = 0.f;
    for (int l2 = tid; l2 < 1024; l2 += 256)
        WaS[l2 >> 4][l2 & 15] = Wa[(size_t)(l2 >> 4) * 515 + b * 16 + (l2 & 15)];
    __syncthreads();

// issue the edge-row load for node nn (block-uniform)
#define XLOAD(nn, XV) do {                                                    \
        int row_;                                                             \
        if (dir == 0) row_ = (nn) * 4 + d_g;                                  \
        else { row_ = ((nn) + 1 + d_g) * 4 + d_g;                             \
               if (row_ > kE - 1) row_ = kE - 1; }                            \
        XV = *(const float4*)(edges + (size_t)row_ * kF + 4 * jl2);           \
    } while (0)

// finish xproj from a prefetched edge vector
#define XFIN(XV, XPOUT, ZXOUT) do {                                           \
        *(float4*)(&x_s[d_g][4 * jl2]) = XV;                                  \
        __syncthreads();                                                      \
        float p0_ = 0.f, p1_ = 0.f, p2_ = 0.f, p3_ = 0.f;                     \
        _Pragma("unroll")                                                     \
        for (int k4_ = 0; k4_ < 16; k4_++) {                                  \
            float4 a0_ = *(const float4*)&x_s[0][d_g * 64 + k4_ * 4];         \
            float4 a1_ = *(const float4*)&x_s[1][d_g * 64 + k4_ * 4];         \
            float4 a2_ = *(const float4*)&x_s[2][d_g * 64 + k4_ * 4];         \
            float4 a3_ = *(const float4*)&x_s[3][d_g * 64 + k4_ * 4];         \
            float w0_ = wih[k4_*4], w1_ = wih[k4_*4+1];                       \
            float w2_ = wih[k4_*4+2], w3_ = wih[k4_*4+3];                     \
            p0_ += w0_*a0_.x + w1_*a0_.y + w2_*a0_.z + w3_*a0_.w;             \
            p1_ += w0_*a1_.x + w1_*a1_.y + w2_*a1_.z + w3_*a1_.w;             \
            p2_ += w0_*a2_.x + w1_*a2_.y + w2_*a2_.z + w3_*a2_.w;             \
            p3_ += w0_*a3_.x + w1_*a3_.y + w2_*a3_.z + w3_*a3_.w;             \
        }                                                                     \
        xpart[d_g][0][jl2] = p0_; xpart[d_g][1][jl2] = p1_;                   \
        xpart[d_g][2][jl2] = p2_; xpart[d_g][3][jl2] = p3_;                   \
        __syncthreads();                                                      \
        XPOUT = biasR + xpart[0][d_g][jl2] + xpart[1][d_g][jl2]               \
                      + xpart[2][d_g][jl2] + xpart[3][d_g][jl2];              \
        ZXOUT = baR + wax0 * x_s[d_g][0] + wax1 * x_s[d_g][1]                 \
                    + wax2 * x_s[d_g][2];                                     \
    } while (0)

    const int i0 = dir ? kN - 1 : 0;
    float xp, zxv;
    {
        float4 xv0;
        XLOAD(i0, xv0);
        XFIN(xv0, xp, zxv);
    }

    for (int t = 0; t < kN; t++) {
        const int i = dir ? kN - 1 - t : t;
        const unsigned stamp = (unsigned)(t + 1);
        const int par = t & 1;

        // ---- prefetch next step's edge row (latency overlaps phases A/B) ----
        float4 xv_n;
        {
            const int nn = (t + 1 < kN) ? (dir ? i - 1 : i + 1) : i;
            XLOAD(nn, xv_n);
        }

        // ---- A: M[iprev] = hprev . Whh^T (own 64 rows) ----
        float acc = 0.f;
        {
            const float* hp = &hprev_p[ks * 132];
            #pragma unroll
            for (int kk = 0; kk < 128; kk += 4) {
                float4 hv = *(const float4*)(hp + kk);
                acc += w[kk] * hv.x + w[kk+1] * hv.y + w[kk+2] * hv.z + w[kk+3] * hv.w;
            }
        }
        acc += __shfl_xor(acc, 1);
        acc += __shfl_xor(acc, 2);
        const int iprev = dir ? i + 1 : i - 1;
        if (ks == 0) Mh[iprev & 3][jl] = acc;
        __syncthreads();

        // ---- B: gates ----
        {
            const int p = dir ? i + 1 + d_g : i - 1 - d_g;
            gl[d_g][jl2] = xp + Mh[p & 3][jl2];
        }
        __syncthreads();
        if (tid < 64) {
            const int d3 = tid >> 4, s3 = tid & 15;
            const int pp = dir ? i + 1 + d3 : i - 1 - d3;
            const bool v3 = dir ? (pp < kN) : (pp >= 0);
            float gi = gl[d3][s3],      gf = gl[d3][16 + s3];
            float gg = gl[d3][32 + s3], go = gl[d3][48 + s3];
            float cp = cring[pp & 3][s3];
            float c = sigm(gf) * cp + sigm(gi) * tanhf(gg);
            float h = sigm(go) * tanhf(c);
            float hm = v3 ? h : 0.f, cm = v3 ? c : 0.f;
            harcl[d3][s3] = hm; carcl[d3][s3] = cm;
            arc[((size_t)i * 4 + d3) * kH + b * 16 + s3] = __float2bfloat16(hm);
            st_pair(hpay + (((dir * 2 + par) * 4 + d3) << 9) + b * 16 + s3, hm, stamp);
        }
        __syncthreads();
        // z partials over own 16 h-dims, publish
        {
            float zp = 0.f;
            #pragma unroll
            for (int ss = 0; ss < 16; ss++) zp += WaS[a_id][ss] * harcl[d_g][ss];
            st_pair(zpay + (((dir * 2 + par) * 32 + b) << 8) + tid, zp, stamp);
        }

        // ---- C: next step's input projection (overlaps publish visibility) ----
        float xp_n, zx_n;
        XFIN(xv_n, xp_n, zx_n);

        // ---- E: batched stamped loads (z + h) ----
        const ull* zb = zpay + (((size_t)(dir * 2 + par) * 32) << 8) + tid;
        ull zv_[32];
        #pragma unroll
        for (int bb = 0; bb < 32; bb++) zv_[bb] = ld_raw(zb + ((size_t)bb << 8));
        const ull* hb = hpay + (((size_t)(dir * 2 + par) * 4) << 9);
        ull hv_[8];
        #pragma unroll
        for (int dd = 0; dd < 4; dd++) {
            hv_[2*dd]   = ld_raw(hb + (dd << 9) + 2 * tid);
            hv_[2*dd+1] = ld_raw(hb + (dd << 9) + 2 * tid + 1);
        }

        // resolve z: batched sweeps with backoff (retries only congest MALL)
        for (;;) {
            bool ok = true;
            #pragma unroll
            for (int bb = 0; bb < 32; bb++)
                ok &= ((unsigned)(zv_[bb] >> 32) == stamp);
            if (ok) break;
            __builtin_amdgcn_s_sleep(2);
            #pragma unroll
            for (int bb = 0; bb < 32; bb++)
                if ((unsigned)(zv_[bb] >> 32) != stamp)
                    zv_[bb] = ld_raw(zb + ((size_t)bb << 8));
        }
        float zsum = 0.f;
        #pragma unroll
        for (int bb = 0; bb < 32; bb++) zsum += __uint_as_float((unsigned)zv_[bb]);

        // resolve h: batched sweeps with backoff
        for (;;) {
            bool ok = true;
            #pragma unroll
            for (int q = 0; q < 8; q++)
                ok &= ((unsigned)(hv_[q] >> 32) == stamp);
            if (ok) break;
            __builtin_amdgcn_s_sleep(2);
            #pragma unroll
            for (int dd = 0; dd < 4; dd++) {
                if ((unsigned)(hv_[2*dd]   >> 32) != stamp) hv_[2*dd]   = ld_raw(hb + (dd << 9) + 2 * tid);
                if ((unsigned)(hv_[2*dd+1] >> 32) != stamp) hv_[2*dd+1] = ld_raw(hb + (dd << 9) + 2 * tid + 1);
            }
        }

        float zv = fmaxf(zsum + zxv, 0.f);
        float lv = WaoR * zv;
        #pragma unroll
        for (int o2 = 1; o2 < 64; o2 <<= 1) lv += __shfl_xor(lv, o2);
        if (a_id == 0) {
            const int pp = dir ? i + 1 + d_g : i - 1 - d_g;
            const bool v3 = dir ? (pp < kN) : (pp >= 0);
            logit_l[d_g] = v3 ? tanhf(lv + baoR) : -1e9f;
        }
        __syncthreads();

        float l0 = logit_l[0], l1 = logit_l[1], l2 = logit_l[2], l3 = logit_l[3];
        float mx = fmaxf(fmaxf(l0, l1), fmaxf(l2, l3));
        float e0 = __expf(l0 - mx), e1 = __expf(l1 - mx);
        float e2 = __expf(l2 - mx), e3 = __expf(l3 - mx);
        float inv = 1.f / (e0 + e1 + e2 + e3);
        float wg[4] = { e0 * inv, e1 * inv, e2 * inv, e3 * inv };

        float hn0 = 0.f, hn1 = 0.f;
        #pragma unroll
        for (int dd = 0; dd < 4; dd++) {
            hn0 += wg[dd] * __uint_as_float((unsigned)hv_[2*dd]);
            hn1 += wg[dd] * __uint_as_float((unsigned)hv_[2*dd+1]);
        }
        {
            const int g = 2 * tid;
            const int ch = g >> 7, wi = g & 127;
            hprev_p[ch * 132 + wi]     = hn0;
            hprev_p[ch * 132 + wi + 1] = hn1;
        }
        if (tid < 16) {
            float cn = wg[0] * carcl[0][tid] + wg[1] * carcl[1][tid]
                     + wg[2] * carcl[2][tid] + wg[3] * carcl[3][tid];
            cring[i & 3][tid] = cn;
        }
        __syncthreads();

        xp = xp_n; zxv = zx_n;
    }
#undef XLOAD
#undef XFIN
}

// ---------------------------------------------------------------------------
// decoder: out[e] += sum_l Wdo[l] * relu(bd[l] + sum_k Wd[l,k] feat[e,k])
// ---------------------------------------------------------------------------
__global__ __launch_bounds__(256) void k_dec(
    const __hip_bfloat16* __restrict__ arc_f, const __hip_bfloat16* __restrict__ arc_b,
    const float* __restrict__ Wd, const float* __restrict__ bd,
    const float* __restrict__ Wdo, float* __restrict__ out) {
    const int e0 = blockIdx.x * 128;
    const int l0 = blockIdx.y * 128;
    __shared__ __align__(16) float As[8][128];
    __shared__ __align__(16) float Bs[8][128];
    const int tid = threadIdx.x;
    const int tx = tid & 15, ty = tid >> 4;
    const int lr = tid & 127, kq = tid >> 7;

    const int e = e0 + lr;
    const int j = e >> 2, d = e & 3;
    const int jb = j - 1 - d;
    const __hip_bfloat16* frow  = arc_f + (size_t)e * kH;
    const __hip_bfloat16* brow2 = (jb >= 0) ? (arc_b + ((size_t)jb * 4 + d) * kH) : nullptr;
    const float* wrow = Wd + (size_t)(l0 + lr) * (2 * kH);

    float acc[8][8] = {};
    for (int k0 = 0; k0 < 2 * kH; k0 += 8) {
        const int kk = k0 + kq * 4;
        float4 av4;
        if (kk < kH) av4 = ld_bf4(frow + kk);
        else if (brow2) av4 = ld_bf4(brow2 + (kk - kH));
        else av4 = make_float4(0.f, 0.f, 0.f, 0.f);
        float4 bv4 = *(const float4*)(wrow + kk);
        __syncthreads();
        As[kq*4+0][lr] = av4.x; As[kq*4+1][lr] = av4.y;
        As[kq*4+2][lr] = av4.z; As[kq*4+3][lr] = av4.w;
        Bs[kq*4+0][lr] = bv4.x; Bs[kq*4+1][lr] = bv4.y;
        Bs[kq*4+2][lr] = bv4.z; Bs[kq*4+3][lr] = bv4.w;
        __syncthreads();
        #pragma unroll
        for (int kt = 0; kt < 8; kt++) {
            __align__(16) float a0[8], b0[8];
            *(float4*)&a0[0] = *(const float4*)&As[kt][ty*8];
            *(float4*)&a0[4] = *(const float4*)&As[kt][ty*8+4];
            *(float4*)&b0[0] = *(const float4*)&Bs[kt][tx*8];
            *(float4*)&b0[4] = *(const float4*)&Bs[kt][tx*8+4];
            #pragma unroll
            for (int mi = 0; mi < 8; mi++)
                #pragma unroll
                for (int ni = 0; ni < 8; ni++)
                    acc[mi][ni] += a0[mi] * b0[ni];
        }
    }
    #pragma unroll
    for (int mi = 0; mi < 8; mi++) {
        float sacc = 0.f;
        #pragma unroll
        for (int ni = 0; ni < 8; ni++) {
            int l = l0 + tx * 8 + ni;
            sacc += Wdo[l] * fmaxf(acc[mi][ni] + bd[l], 0.f);
        }
        sacc += __shfl_xor(sacc, 1);
        sacc += __shfl_xor(sacc, 2);
        sacc += __shfl_xor(sacc, 4);
        sacc += __shfl_xor(sacc, 8);
        if (tx == 0) atomicAdd(out + e0 + ty * 8 + mi, sacc);
    }
}

// ---------------------------------------------------------------------------
extern "C" void kernel_launch(void* const* d_in, const int* in_sizes, int n_in,
                              void* d_out, int out_size, void* d_ws, size_t ws_size,
                              hipStream_t stream) {
    const float* edges = (const float*)d_in[0];
    const float* Wih_f = (const float*)d_in[1];
    const float* Whh_f = (const float*)d_in[2];
    const float* b_f   = (const float*)d_in[3];
    const float* Wih_b = (const float*)d_in[4];
    const float* Whh_b = (const float*)d_in[5];
    const float* b_b   = (const float*)d_in[6];
    const float* Wa    = (const float*)d_in[7];
    const float* ba    = (const float*)d_in[8];
    const float* Wao   = (const float*)d_in[9];
    const float* bao   = (const float*)d_in[10];
    const float* Wd    = (const float*)d_in[11];
    const float* bd    = (const float*)d_in[12];
    const float* Wdo   = (const float*)d_in[13];
    const float* bdo   = (const float*)d_in[14];
    float* out = (float*)d_out;

    char* ws = (char*)d_ws;
    size_t off = 0;
    __hip_bfloat16* arc_f = (__hip_bfloat16*)(ws + off); off += (size_t)kE * kH * 2;  // 32 MB
    __hip_bfloat16* arc_b = (__hip_bfloat16*)(ws + off); off += (size_t)kE * kH * 2;  // 32 MB
    ull* hpay = (ull*)(ws + off); off += (size_t)2 * 2 * 4 * kH * 8;                  // 64 KB
    ull* zpay = (ull*)(ws + off); off += (size_t)2 * 2 * 32 * 256 * 8;                // 256 KB
    int* claims = (int*)(ws + off); off += 64;

    if (ws_size < off) {
        hipLaunchKernelGGL(k_zero, dim3((kE + 255) / 256), dim3(256), 0, stream, out);
        return;
    }

    hipLaunchKernelGGL(k_init, dim3(128), dim3(256), 0, stream,
                       out, bdo, hpay, zpay, claims);
    hipLaunchKernelGGL(k_recur, dim3(512), dim3(256), 0, stream,
                       edges, Wih_f, Whh_f, b_f, Wih_b, Whh_b, b_b,
                       Wa, ba, Wao, bao, arc_f, arc_b, hpay, zpay, claims);
    hipLaunchKernelGGL(k_dec, dim3(kE / 128, kL / 128), dim3(256), 0, stream,
                       arc_f, arc_b, Wd, bd, Wdo, out);
}